// Round 14
// baseline (159.618 us; speedup 1.0000x reference)
//
#include <hip/hip_runtime.h>
#include <hip/hip_bf16.h>

typedef __bf16 bf16x8 __attribute__((ext_vector_type(8)));
typedef float f32x4 __attribute__((ext_vector_type(4)));
typedef float f32x16 __attribute__((ext_vector_type(16)));
using u16 = unsigned short;
using u32 = unsigned int;

#define LDSS 72  // padded LDS row stride in bf16 elems

__device__ __forceinline__ u16 f2bf(float f) {
  union { float f; u32 u; } v; v.f = f;
  u32 r = v.u + 0x7fffu + ((v.u >> 16) & 1u);   // RNE
  return (u16)(r >> 16);
}

__device__ __forceinline__ u32 cvt_pk_bf16(float lo, float hi) {
  u32 r;
  asm("v_cvt_pk_bf16_f32 %0, %1, %2" : "=v"(r) : "v"(lo), "v"(hi));
  return r;
}

__device__ __forceinline__ uint4 pack8(float4 a, float4 b) {
  u16 t[8];
  t[0] = f2bf(a.x); t[1] = f2bf(a.y); t[2] = f2bf(a.z); t[3] = f2bf(a.w);
  t[4] = f2bf(b.x); t[5] = f2bf(b.y); t[6] = f2bf(b.z); t[7] = f2bf(b.w);
  return *(uint4*)t;
}

// weights (512x512, stored (in,out)) -> bf16 transposed (out,in), LDS-tiled.
__global__ __launch_bounds__(256) void cast_wT_kernel(
    const float* __restrict__ w0, const float* __restrict__ w1,
    const float* __restrict__ w2, const float* __restrict__ w3,
    u16* __restrict__ t0, u16* __restrict__ t1,
    u16* __restrict__ t2, u16* __restrict__ t3) {
  __shared__ u16 tl[64][72];
  int wi = blockIdx.z;
  const float* w; u16* t;
  if (wi == 0)      { w = w0; t = t0; }
  else if (wi == 1) { w = w1; t = t1; }
  else if (wi == 2) { w = w2; t = t2; }
  else              { w = w3; t = t3; }
  int r0 = blockIdx.x * 64, c0 = blockIdx.y * 64;
  int tid = threadIdx.x;
  int row = tid >> 2, q = tid & 3;
#pragma unroll
  for (int j = 0; j < 4; j++) {
    float4 f = *(const float4*)&w[(r0 + row) * 512 + c0 + q * 16 + j * 4];
    tl[row][q * 16 + j * 4 + 0] = f2bf(f.x);
    tl[row][q * 16 + j * 4 + 1] = f2bf(f.y);
    tl[row][q * 16 + j * 4 + 2] = f2bf(f.z);
    tl[row][q * 16 + j * 4 + 3] = f2bf(f.w);
  }
  __syncthreads();
  int crow = tid >> 2;
  u16 tmp[16];
#pragma unroll
  for (int j = 0; j < 16; j++) tmp[j] = tl[q * 16 + j][crow];
  *(uint4*)&t[(c0 + crow) * 512 + r0 + q * 16]     = *(uint4*)&tmp[0];
  *(uint4*)&t[(c0 + crow) * 512 + r0 + q * 16 + 8] = *(uint4*)&tmp[8];
}

// ---------------- QKV projection GEMM: 64x64 tile, reg-prefetch ----------------
// A-side reads f32 x directly (cast fused into staging).
__global__ __launch_bounds__(256) void proj_kernel(
    const float* __restrict__ x,
    const u16* __restrict__ wqT, const u16* __restrict__ wkT, const u16* __restrict__ wvT,
    const float* __restrict__ bq, const float* __restrict__ bk, const float* __restrict__ bv,
    u16* __restrict__ Q, u16* __restrict__ K, u16* __restrict__ Vt) {
  __shared__ u16 Alds[64 * LDSS];
  __shared__ u16 Blds[64 * LDSS];
  int which = blockIdx.z;
  const u16* wT; const float* bias; u16* out;
  if (which == 0)      { wT = wqT; bias = bq; out = Q; }
  else if (which == 1) { wT = wkT; bias = bk; out = K; }
  else                 { wT = wvT; bias = bv; out = Vt; }

  int m0 = blockIdx.y * 64;
  int n0 = blockIdx.x * 64;
  int tid = threadIdx.x;
  int lane = tid & 63, w = tid >> 6;
  int wm = w >> 1, wn = w & 1;
  int l15 = lane & 15, l4 = lane >> 4;

  int r0 = tid >> 3, c8 = (tid & 7) * 8;

  float4 af00 = *(const float4*)&x[(size_t)(m0 + r0) * 512 + c8];
  float4 af01 = *(const float4*)&x[(size_t)(m0 + r0) * 512 + c8 + 4];
  float4 af10 = *(const float4*)&x[(size_t)(m0 + r0 + 32) * 512 + c8];
  float4 af11 = *(const float4*)&x[(size_t)(m0 + r0 + 32) * 512 + c8 + 4];
  uint4 br0 = *(const uint4*)&wT[(n0 + r0) * 512 + c8];
  uint4 br1 = *(const uint4*)&wT[(n0 + r0 + 32) * 512 + c8];

  f32x4 acc[2][2] = {};
  for (int ks = 0; ks < 8; ks++) {
    __syncthreads();
    *(uint4*)&Alds[r0 * LDSS + c8]        = pack8(af00, af01);
    *(uint4*)&Alds[(r0 + 32) * LDSS + c8] = pack8(af10, af11);
    *(uint4*)&Blds[r0 * LDSS + c8]        = br0;
    *(uint4*)&Blds[(r0 + 32) * LDSS + c8] = br1;
    __syncthreads();
    if (ks < 7) {
      int k0 = (ks + 1) * 64;
      af00 = *(const float4*)&x[(size_t)(m0 + r0) * 512 + k0 + c8];
      af01 = *(const float4*)&x[(size_t)(m0 + r0) * 512 + k0 + c8 + 4];
      af10 = *(const float4*)&x[(size_t)(m0 + r0 + 32) * 512 + k0 + c8];
      af11 = *(const float4*)&x[(size_t)(m0 + r0 + 32) * 512 + k0 + c8 + 4];
      br0 = *(const uint4*)&wT[(n0 + r0) * 512 + k0 + c8];
      br1 = *(const uint4*)&wT[(n0 + r0 + 32) * 512 + k0 + c8];
    }
#pragma unroll
    for (int kk = 0; kk < 2; kk++) {
      bf16x8 a[2], b[2];
#pragma unroll
      for (int f = 0; f < 2; f++) {
        a[f] = *(const bf16x8*)&Alds[(wm * 32 + f * 16 + l15) * LDSS + kk * 32 + l4 * 8];
        b[f] = *(const bf16x8*)&Blds[(wn * 32 + f * 16 + l15) * LDSS + kk * 32 + l4 * 8];
      }
#pragma unroll
      for (int fm = 0; fm < 2; fm++)
#pragma unroll
        for (int fn = 0; fn < 2; fn++) {
          if (which == 2)
            acc[fm][fn] = __builtin_amdgcn_mfma_f32_16x16x32_bf16(b[fn], a[fm], acc[fm][fn], 0, 0, 0);
          else
            acc[fm][fn] = __builtin_amdgcn_mfma_f32_16x16x32_bf16(a[fm], b[fn], acc[fm][fn], 0, 0, 0);
        }
    }
  }
  int bidx = m0 >> 11;
  int head = n0 >> 6;
  if (which == 2) {
#pragma unroll
    for (int fm = 0; fm < 2; fm++)
#pragma unroll
      for (int fn = 0; fn < 2; fn++)
#pragma unroll
        for (int r = 0; r < 4; r++) {
          int drow = wn * 32 + fn * 16 + l4 * 4 + r;
          int col  = wm * 32 + fm * 16 + l15;
          float vv = acc[fm][fn][r] + bias[n0 + drow];
          out[((size_t)(bidx * 8 + head) * 64 + drow) * 2048 + (m0 & 2047) + col] = f2bf(vv);
        }
  } else {
#pragma unroll
    for (int fm = 0; fm < 2; fm++)
#pragma unroll
      for (int fn = 0; fn < 2; fn++)
#pragma unroll
        for (int r = 0; r < 4; r++) {
          int row = wm * 32 + fm * 16 + l4 * 4 + r;
          int col = wn * 32 + fn * 16 + l15;
          int nrow = (m0 & 2047) + row;
          float vv = acc[fm][fn][r] + bias[n0 + col];
          out[(((size_t)(bidx * 8 + head) * 2048) + nrow) * 64 + col] = f2bf(vv);
        }
  }
}

// ---------------- flash attention: round-6 exact (94 us, best measured) ----------------
// 4 waves x 32 q-rows = qtile 128; KV tile 64; grid 512.
__global__ __launch_bounds__(256, 2) void attn_kernel(
    const u16* __restrict__ Q, const u16* __restrict__ K, const u16* __restrict__ Vt,
    const float* __restrict__ bias, u16* __restrict__ O) {
  __shared__ u16 Klds[64 * LDSS];
  __shared__ u16 Vtlds[64 * LDSS];

  int qt = blockIdx.x, h = blockIdx.y, b = blockIdx.z;
  int tid = threadIdx.x;
  int lane = tid & 63, w = tid >> 6;
  int l31 = lane & 31, hi = lane >> 5;
  int qrow = qt * 128 + w * 32 + l31;

  const u16* Qbh  = Q  + (size_t)(b * 8 + h) * 2048 * 64;
  const u16* Kbh  = K  + (size_t)(b * 8 + h) * 2048 * 64;
  const u16* Vtbh = Vt + (size_t)(b * 8 + h) * 64 * 2048;
  const float* biasq = bias + (size_t)b * 2048 * 2048 + (size_t)qrow * 2048;

  bf16x8 qf[4];
#pragma unroll
  for (int dk = 0; dk < 4; dk++)
    qf[dk] = *(const bf16x8*)&Qbh[qrow * 64 + dk * 16 + hi * 8];

  f32x16 o[2] = {};
  float mrow = -1e30f, lrow = 0.f;

  int r0 = tid >> 3, c8 = (tid & 7) * 8;

  uint4 kr0 = *(const uint4*)&Kbh[r0 * 64 + c8];
  uint4 kr1 = *(const uint4*)&Kbh[(32 + r0) * 64 + c8];
  uint4 vr0 = *(const uint4*)&Vtbh[r0 * 2048 + c8];
  uint4 vr1 = *(const uint4*)&Vtbh[(r0 + 32) * 2048 + c8];
  float4 bb[8];
#pragma unroll
  for (int kt = 0; kt < 2; kt++)
#pragma unroll
    for (int g = 0; g < 4; g++)
      bb[kt * 4 + g] = *(const float4*)&biasq[kt * 32 + 8 * g + 4 * hi];

  for (int t = 0; t < 32; t++) {
    __syncthreads();
    *(uint4*)&Klds[r0 * LDSS + c8]         = kr0;
    *(uint4*)&Klds[(r0 + 32) * LDSS + c8]  = kr1;
    *(uint4*)&Vtlds[r0 * LDSS + c8]        = vr0;
    *(uint4*)&Vtlds[(r0 + 32) * LDSS + c8] = vr1;
    __syncthreads();

    bool pf = (t < 31);
    if (pf) {
      kr0 = *(const uint4*)&Kbh[((t + 1) * 64 + r0) * 64 + c8];
      kr1 = *(const uint4*)&Kbh[((t + 1) * 64 + 32 + r0) * 64 + c8];
      vr0 = *(const uint4*)&Vtbh[r0 * 2048 + (t + 1) * 64 + c8];
      vr1 = *(const uint4*)&Vtbh[(r0 + 32) * 2048 + (t + 1) * 64 + c8];
    }

    f32x16 s[2] = {};
    __builtin_amdgcn_s_setprio(1);
#pragma unroll
    for (int dk = 0; dk < 4; dk++) {
      bf16x8 a0 = *(const bf16x8*)&Klds[l31 * LDSS + dk * 16 + hi * 8];
      s[0] = __builtin_amdgcn_mfma_f32_32x32x16_bf16(a0, qf[dk], s[0], 0, 0, 0);
      bf16x8 a1 = *(const bf16x8*)&Klds[(32 + l31) * LDSS + dk * 16 + hi * 8];
      s[1] = __builtin_amdgcn_mfma_f32_32x32x16_bf16(a1, qf[dk], s[1], 0, 0, 0);
    }
    __builtin_amdgcn_s_setprio(0);

    float m = -1e30f;
#pragma unroll
    for (int kt = 0; kt < 2; kt++)
#pragma unroll
      for (int g = 0; g < 4; g++) {
        float4 bv4 = bb[kt * 4 + g];
#pragma unroll
        for (int j = 0; j < 4; j++) {
          float val = s[kt][g * 4 + j] * 0.125f + ((const float*)&bv4)[j];
          s[kt][g * 4 + j] = val;
          m = fmaxf(m, val);
        }
      }
    m = fmaxf(m, __shfl_xor(m, 32));

    if (!__all(m <= mrow + 8.0f)) {
      float mnew = fmaxf(mrow, m);
      float corr = __expf(mrow - mnew);
      mrow = mnew;
      lrow *= corr;
#pragma unroll
      for (int dt = 0; dt < 2; dt++)
#pragma unroll
        for (int i = 0; i < 16; i++) o[dt][i] *= corr;
    }

    u32 c[2][8];
    float sum = 0.f;
#pragma unroll
    for (int kt = 0; kt < 2; kt++)
#pragma unroll
      for (int g = 0; g < 4; g++) {
        float p0 = __expf(s[kt][g * 4 + 0] - mrow);
        float p1 = __expf(s[kt][g * 4 + 1] - mrow);
        float p2 = __expf(s[kt][g * 4 + 2] - mrow);
        float p3 = __expf(s[kt][g * 4 + 3] - mrow);
        sum += (p0 + p1) + (p2 + p3);
        c[kt][2 * g]     = cvt_pk_bf16(p0, p1);
        c[kt][2 * g + 1] = cvt_pk_bf16(p2, p3);
      }
    sum += __shfl_xor(sum, 32);
    lrow += sum;

    u32 dx[2][8];
#pragma unroll
    for (int kt = 0; kt < 2; kt++)
#pragma unroll
      for (int j = 0; j < 8; j++)
        dx[kt][j] = (u32)__shfl_xor((int)c[kt][j], 32);

    if (pf) {
#pragma unroll
      for (int kt = 0; kt < 2; kt++)
#pragma unroll
        for (int g = 0; g < 4; g++)
          bb[kt * 4 + g] = *(const float4*)&biasq[(t + 1) * 64 + kt * 32 + 8 * g + 4 * hi];
    }

    __builtin_amdgcn_s_setprio(1);
#pragma unroll
    for (int kk = 0; kk < 4; kk++) {
      const int kt = kk >> 1, jA = 4 * (kk & 1);
      union { u32 u[4]; bf16x8 v; } pfg;
      pfg.u[0] = hi ? dx[kt][jA + 2] : c[kt][jA];
      pfg.u[1] = hi ? dx[kt][jA + 3] : c[kt][jA + 1];
      pfg.u[2] = hi ? c[kt][jA + 2]  : dx[kt][jA];
      pfg.u[3] = hi ? c[kt][jA + 3]  : dx[kt][jA + 1];
#pragma unroll
      for (int dt = 0; dt < 2; dt++) {
        bf16x8 va = *(const bf16x8*)&Vtlds[(dt * 32 + l31) * LDSS + kk * 16 + hi * 8];
        o[dt] = __builtin_amdgcn_mfma_f32_32x32x16_bf16(va, pfg.v, o[dt], 0, 0, 0);
      }
    }
    __builtin_amdgcn_s_setprio(0);
  }

  float inv = 1.0f / lrow;
  size_t obase = (size_t)(b * 2048 + qrow) * 512 + h * 64;
#pragma unroll
  for (int dt = 0; dt < 2; dt++)
#pragma unroll
    for (int g = 0; g < 4; g++) {
      uint2 pr;
      pr.x = cvt_pk_bf16(o[dt][4 * g + 0] * inv, o[dt][4 * g + 1] * inv);
      pr.y = cvt_pk_bf16(o[dt][4 * g + 2] * inv, o[dt][4 * g + 3] * inv);
      *(uint2*)&O[obase + dt * 32 + 8 * g + 4 * hi] = pr;
    }
}

// ---------------- output projection: 64x64 tile, reg-prefetch ----------------
__global__ __launch_bounds__(256) void outproj_kernel(
    const u16* __restrict__ Ob, const u16* __restrict__ woT,
    const float* __restrict__ bo, float* __restrict__ out) {
  __shared__ u16 Alds[64 * LDSS];
  __shared__ u16 Blds[64 * LDSS];
  int m0 = blockIdx.y * 64;
  int n0 = blockIdx.x * 64;
  int tid = threadIdx.x;
  int lane = tid & 63, w = tid >> 6;
  int wm = w >> 1, wn = w & 1;
  int l15 = lane & 15, l4 = lane >> 4;

  int r0 = tid >> 3, c8 = (tid & 7) * 8;
  uint4 ar0 = *(const uint4*)&Ob[(m0 + r0) * 512 + c8];
  uint4 ar1 = *(const uint4*)&Ob[(m0 + r0 + 32) * 512 + c8];
  uint4 br0 = *(const uint4*)&woT[(n0 + r0) * 512 + c8];
  uint4 br1 = *(const uint4*)&woT[(n0 + r0 + 32) * 512 + c8];

  f32x4 acc[2][2] = {};
  for (int ks = 0; ks < 8; ks++) {
    __syncthreads();
    *(uint4*)&Alds[r0 * LDSS + c8]        = ar0;
    *(uint4*)&Alds[(r0 + 32) * LDSS + c8] = ar1;
    *(uint4*)&Blds[r0 * LDSS + c8]        = br0;
    *(uint4*)&Blds[(r0 + 32) * LDSS + c8] = br1;
    __syncthreads();
    if (ks < 7) {
      int k0 = (ks + 1) * 64;
      ar0 = *(const uint4*)&Ob[(m0 + r0) * 512 + k0 + c8];
      ar1 = *(const uint4*)&Ob[(m0 + r0 + 32) * 512 + k0 + c8];
      br0 = *(const uint4*)&woT[(n0 + r0) * 512 + k0 + c8];
      br1 = *(const uint4*)&woT[(n0 + r0 + 32) * 512 + k0 + c8];
    }
#pragma unroll
    for (int kk = 0; kk < 2; kk++) {
      bf16x8 a[2], bfr[2];
#pragma unroll
      for (int f = 0; f < 2; f++) {
        a[f] = *(const bf16x8*)&Alds[(wm * 32 + f * 16 + l15) * LDSS + kk * 32 + l4 * 8];
        bfr[f] = *(const bf16x8*)&Blds[(wn * 32 + f * 16 + l15) * LDSS + kk * 32 + l4 * 8];
      }
#pragma unroll
      for (int fm = 0; fm < 2; fm++)
#pragma unroll
        for (int fn = 0; fn < 2; fn++)
          acc[fm][fn] = __builtin_amdgcn_mfma_f32_16x16x32_bf16(a[fm], bfr[fn], acc[fm][fn], 0, 0, 0);
    }
  }
#pragma unroll
  for (int fm = 0; fm < 2; fm++)
#pragma unroll
    for (int fn = 0; fn < 2; fn++)
#pragma unroll
      for (int r = 0; r < 4; r++) {
        int row = wm * 32 + fm * 16 + l4 * 4 + r;
        int col = wn * 32 + fn * 16 + l15;
        out[(size_t)(m0 + row) * 512 + n0 + col] = acc[fm][fn][r] + bo[n0 + col];
      }
}

extern "C" void kernel_launch(void* const* d_in, const int* in_sizes, int n_in,
                              void* d_out, int out_size, void* d_ws, size_t ws_size,
                              hipStream_t stream) {
  const float* x    = (const float*)d_in[0];
  const float* bias = (const float*)d_in[1];
  const float* wq   = (const float*)d_in[2];
  const float* bq   = (const float*)d_in[3];
  const float* wk   = (const float*)d_in[4];
  const float* bk   = (const float*)d_in[5];
  const float* wv   = (const float*)d_in[6];
  const float* bv   = (const float*)d_in[7];
  const float* wo   = (const float*)d_in[8];
  const float* bo   = (const float*)d_in[9];
  float* out = (float*)d_out;

  char* ws = (char*)d_ws;
  u16* wqT = (u16*)(ws + 8388608);
  u16* wkT = (u16*)(ws + 8912896);
  u16* wvT = (u16*)(ws + 9437184);
  u16* woT = (u16*)(ws + 9961472);
  u16* Qb  = (u16*)(ws + 10485760);
  u16* Kb  = (u16*)(ws + 18874368);
  u16* VtB = (u16*)(ws + 27262976);
  u16* Ob  = (u16*)(ws + 35651584);

  hipLaunchKernelGGL(cast_wT_kernel, dim3(8, 8, 4), dim3(256), 0, stream,
                     wq, wk, wv, wo, wqT, wkT, wvT, woT);
  hipLaunchKernelGGL(proj_kernel, dim3(8, 128, 3), dim3(256), 0, stream,
                     x, wqT, wkT, wvT, bq, bk, bv, Qb, Kb, VtB);
  hipLaunchKernelGGL(attn_kernel, dim3(16, 8, 4), dim3(256), 0, stream,
                     Qb, Kb, VtB, bias, Ob);
  hipLaunchKernelGGL(outproj_kernel, dim3(8, 128), dim3(256), 0, stream,
                     Ob, woT, bo, out);
}

// Round 15
// 135.053 us; speedup vs baseline: 1.1819x; 1.1819x over previous
//
#include <hip/hip_runtime.h>
#include <hip/hip_bf16.h>

typedef __bf16 bf16x8 __attribute__((ext_vector_type(8)));
typedef float f32x4 __attribute__((ext_vector_type(4)));
typedef float f32x16 __attribute__((ext_vector_type(16)));
using u16 = unsigned short;
using u32 = unsigned int;

#define LDSS 72  // padded LDS row stride in bf16 elems

__device__ __forceinline__ u16 f2bf(float f) {
  union { float f; u32 u; } v; v.f = f;
  u32 r = v.u + 0x7fffu + ((v.u >> 16) & 1u);   // RNE
  return (u16)(r >> 16);
}

__device__ __forceinline__ u32 cvt_pk_bf16(float lo, float hi) {
  u32 r;
  asm("v_cvt_pk_bf16_f32 %0, %1, %2" : "=v"(r) : "v"(lo), "v"(hi));
  return r;
}

// ---------------- cast kernels ----------------
__global__ void cast_x_kernel(const float* __restrict__ x, u16* __restrict__ xb) {
  int i = (blockIdx.x * 256 + threadIdx.x) * 8;
  float4 f0 = *(const float4*)&x[i];
  float4 f1 = *(const float4*)&x[i + 4];
  u16 u[8];
  u[0] = f2bf(f0.x); u[1] = f2bf(f0.y); u[2] = f2bf(f0.z); u[3] = f2bf(f0.w);
  u[4] = f2bf(f1.x); u[5] = f2bf(f1.y); u[6] = f2bf(f1.z); u[7] = f2bf(f1.w);
  *(uint4*)&xb[i] = *(uint4*)u;
}

// weights (512x512, stored (in,out)) -> bf16 transposed (out,in), LDS-tiled.
__global__ __launch_bounds__(256) void cast_wT_kernel(
    const float* __restrict__ w0, const float* __restrict__ w1,
    const float* __restrict__ w2, const float* __restrict__ w3,
    u16* __restrict__ t0, u16* __restrict__ t1,
    u16* __restrict__ t2, u16* __restrict__ t3) {
  __shared__ u16 tl[64][72];
  int wi = blockIdx.z;
  const float* w; u16* t;
  if (wi == 0)      { w = w0; t = t0; }
  else if (wi == 1) { w = w1; t = t1; }
  else if (wi == 2) { w = w2; t = t2; }
  else              { w = w3; t = t3; }
  int r0 = blockIdx.x * 64, c0 = blockIdx.y * 64;
  int tid = threadIdx.x;
  int row = tid >> 2, q = tid & 3;
#pragma unroll
  for (int j = 0; j < 4; j++) {
    float4 f = *(const float4*)&w[(r0 + row) * 512 + c0 + q * 16 + j * 4];
    tl[row][q * 16 + j * 4 + 0] = f2bf(f.x);
    tl[row][q * 16 + j * 4 + 1] = f2bf(f.y);
    tl[row][q * 16 + j * 4 + 2] = f2bf(f.z);
    tl[row][q * 16 + j * 4 + 3] = f2bf(f.w);
  }
  __syncthreads();
  int crow = tid >> 2;
  u16 tmp[16];
#pragma unroll
  for (int j = 0; j < 16; j++) tmp[j] = tl[q * 16 + j][crow];
  *(uint4*)&t[(c0 + crow) * 512 + r0 + q * 16]     = *(uint4*)&tmp[0];
  *(uint4*)&t[(c0 + crow) * 512 + r0 + q * 16 + 8] = *(uint4*)&tmp[8];
}

// ---------------- QKV projection GEMM: 64x64 tile, reg-prefetch ----------------
__global__ __launch_bounds__(256) void proj_kernel(
    const u16* __restrict__ xb,
    const u16* __restrict__ wqT, const u16* __restrict__ wkT, const u16* __restrict__ wvT,
    const float* __restrict__ bq, const float* __restrict__ bk, const float* __restrict__ bv,
    u16* __restrict__ Q, u16* __restrict__ K, u16* __restrict__ Vt) {
  __shared__ u16 Alds[64 * LDSS];
  __shared__ u16 Blds[64 * LDSS];
  int which = blockIdx.z;
  const u16* wT; const float* bias; u16* out;
  if (which == 0)      { wT = wqT; bias = bq; out = Q; }
  else if (which == 1) { wT = wkT; bias = bk; out = K; }
  else                 { wT = wvT; bias = bv; out = Vt; }

  int m0 = blockIdx.y * 64;
  int n0 = blockIdx.x * 64;
  int tid = threadIdx.x;
  int lane = tid & 63, w = tid >> 6;
  int wm = w >> 1, wn = w & 1;
  int l15 = lane & 15, l4 = lane >> 4;

  int r0 = tid >> 3, c8 = (tid & 7) * 8;

  uint4 ar0 = *(const uint4*)&xb[(m0 + r0) * 512 + c8];
  uint4 ar1 = *(const uint4*)&xb[(m0 + r0 + 32) * 512 + c8];
  uint4 br0 = *(const uint4*)&wT[(n0 + r0) * 512 + c8];
  uint4 br1 = *(const uint4*)&wT[(n0 + r0 + 32) * 512 + c8];

  f32x4 acc[2][2] = {};
  for (int ks = 0; ks < 8; ks++) {
    __syncthreads();
    *(uint4*)&Alds[r0 * LDSS + c8]        = ar0;
    *(uint4*)&Alds[(r0 + 32) * LDSS + c8] = ar1;
    *(uint4*)&Blds[r0 * LDSS + c8]        = br0;
    *(uint4*)&Blds[(r0 + 32) * LDSS + c8] = br1;
    __syncthreads();
    if (ks < 7) {
      int k0 = (ks + 1) * 64;
      ar0 = *(const uint4*)&xb[(m0 + r0) * 512 + k0 + c8];
      ar1 = *(const uint4*)&xb[(m0 + r0 + 32) * 512 + k0 + c8];
      br0 = *(const uint4*)&wT[(n0 + r0) * 512 + k0 + c8];
      br1 = *(const uint4*)&wT[(n0 + r0 + 32) * 512 + k0 + c8];
    }
#pragma unroll
    for (int kk = 0; kk < 2; kk++) {
      bf16x8 a[2], b[2];
#pragma unroll
      for (int f = 0; f < 2; f++) {
        a[f] = *(const bf16x8*)&Alds[(wm * 32 + f * 16 + l15) * LDSS + kk * 32 + l4 * 8];
        b[f] = *(const bf16x8*)&Blds[(wn * 32 + f * 16 + l15) * LDSS + kk * 32 + l4 * 8];
      }
#pragma unroll
      for (int fm = 0; fm < 2; fm++)
#pragma unroll
        for (int fn = 0; fn < 2; fn++) {
          if (which == 2)
            acc[fm][fn] = __builtin_amdgcn_mfma_f32_16x16x32_bf16(b[fn], a[fm], acc[fm][fn], 0, 0, 0);
          else
            acc[fm][fn] = __builtin_amdgcn_mfma_f32_16x16x32_bf16(a[fm], b[fn], acc[fm][fn], 0, 0, 0);
        }
    }
  }
  int bidx = m0 >> 11;
  int head = n0 >> 6;
  if (which == 2) {
#pragma unroll
    for (int fm = 0; fm < 2; fm++)
#pragma unroll
      for (int fn = 0; fn < 2; fn++)
#pragma unroll
        for (int r = 0; r < 4; r++) {
          int drow = wn * 32 + fn * 16 + l4 * 4 + r;
          int col  = wm * 32 + fm * 16 + l15;
          float vv = acc[fm][fn][r] + bias[n0 + drow];
          out[((size_t)(bidx * 8 + head) * 64 + drow) * 2048 + (m0 & 2047) + col] = f2bf(vv);
        }
  } else {
#pragma unroll
    for (int fm = 0; fm < 2; fm++)
#pragma unroll
      for (int fn = 0; fn < 2; fn++)
#pragma unroll
        for (int r = 0; r < 4; r++) {
          int row = wm * 32 + fm * 16 + l4 * 4 + r;
          int col = wn * 32 + fn * 16 + l15;
          int nrow = (m0 & 2047) + row;
          float vv = acc[fm][fn][r] + bias[n0 + col];
          out[(((size_t)(bidx * 8 + head) * 2048) + nrow) * 64 + col] = f2bf(vv);
        }
  }
}

// ---------------- flash attention: round-6 exact (94 us, best measured) ----------------
// 4 waves x 32 q-rows = qtile 128; KV tile 64; grid 512.
__global__ __launch_bounds__(256, 2) void attn_kernel(
    const u16* __restrict__ Q, const u16* __restrict__ K, const u16* __restrict__ Vt,
    const float* __restrict__ bias, u16* __restrict__ O) {
  __shared__ u16 Klds[64 * LDSS];
  __shared__ u16 Vtlds[64 * LDSS];

  int qt = blockIdx.x, h = blockIdx.y, b = blockIdx.z;
  int tid = threadIdx.x;
  int lane = tid & 63, w = tid >> 6;
  int l31 = lane & 31, hi = lane >> 5;
  int qrow = qt * 128 + w * 32 + l31;

  const u16* Qbh  = Q  + (size_t)(b * 8 + h) * 2048 * 64;
  const u16* Kbh  = K  + (size_t)(b * 8 + h) * 2048 * 64;
  const u16* Vtbh = Vt + (size_t)(b * 8 + h) * 64 * 2048;
  const float* biasq = bias + (size_t)b * 2048 * 2048 + (size_t)qrow * 2048;

  bf16x8 qf[4];
#pragma unroll
  for (int dk = 0; dk < 4; dk++)
    qf[dk] = *(const bf16x8*)&Qbh[qrow * 64 + dk * 16 + hi * 8];

  f32x16 o[2] = {};
  float mrow = -1e30f, lrow = 0.f;

  int r0 = tid >> 3, c8 = (tid & 7) * 8;

  uint4 kr0 = *(const uint4*)&Kbh[r0 * 64 + c8];
  uint4 kr1 = *(const uint4*)&Kbh[(32 + r0) * 64 + c8];
  uint4 vr0 = *(const uint4*)&Vtbh[r0 * 2048 + c8];
  uint4 vr1 = *(const uint4*)&Vtbh[(r0 + 32) * 2048 + c8];
  float4 bb[8];
#pragma unroll
  for (int kt = 0; kt < 2; kt++)
#pragma unroll
    for (int g = 0; g < 4; g++)
      bb[kt * 4 + g] = *(const float4*)&biasq[kt * 32 + 8 * g + 4 * hi];

  for (int t = 0; t < 32; t++) {
    __syncthreads();
    *(uint4*)&Klds[r0 * LDSS + c8]         = kr0;
    *(uint4*)&Klds[(r0 + 32) * LDSS + c8]  = kr1;
    *(uint4*)&Vtlds[r0 * LDSS + c8]        = vr0;
    *(uint4*)&Vtlds[(r0 + 32) * LDSS + c8] = vr1;
    __syncthreads();

    bool pf = (t < 31);
    if (pf) {
      kr0 = *(const uint4*)&Kbh[((t + 1) * 64 + r0) * 64 + c8];
      kr1 = *(const uint4*)&Kbh[((t + 1) * 64 + 32 + r0) * 64 + c8];
      vr0 = *(const uint4*)&Vtbh[r0 * 2048 + (t + 1) * 64 + c8];
      vr1 = *(const uint4*)&Vtbh[(r0 + 32) * 2048 + (t + 1) * 64 + c8];
    }

    f32x16 s[2] = {};
    __builtin_amdgcn_s_setprio(1);
#pragma unroll
    for (int dk = 0; dk < 4; dk++) {
      bf16x8 a0 = *(const bf16x8*)&Klds[l31 * LDSS + dk * 16 + hi * 8];
      s[0] = __builtin_amdgcn_mfma_f32_32x32x16_bf16(a0, qf[dk], s[0], 0, 0, 0);
      bf16x8 a1 = *(const bf16x8*)&Klds[(32 + l31) * LDSS + dk * 16 + hi * 8];
      s[1] = __builtin_amdgcn_mfma_f32_32x32x16_bf16(a1, qf[dk], s[1], 0, 0, 0);
    }
    __builtin_amdgcn_s_setprio(0);

    float m = -1e30f;
#pragma unroll
    for (int kt = 0; kt < 2; kt++)
#pragma unroll
      for (int g = 0; g < 4; g++) {
        float4 bv4 = bb[kt * 4 + g];
#pragma unroll
        for (int j = 0; j < 4; j++) {
          float val = s[kt][g * 4 + j] * 0.125f + ((const float*)&bv4)[j];
          s[kt][g * 4 + j] = val;
          m = fmaxf(m, val);
        }
      }
    m = fmaxf(m, __shfl_xor(m, 32));

    if (!__all(m <= mrow + 8.0f)) {
      float mnew = fmaxf(mrow, m);
      float corr = __expf(mrow - mnew);
      mrow = mnew;
      lrow *= corr;
#pragma unroll
      for (int dt = 0; dt < 2; dt++)
#pragma unroll
        for (int i = 0; i < 16; i++) o[dt][i] *= corr;
    }

    u32 c[2][8];
    float sum = 0.f;
#pragma unroll
    for (int kt = 0; kt < 2; kt++)
#pragma unroll
      for (int g = 0; g < 4; g++) {
        float p0 = __expf(s[kt][g * 4 + 0] - mrow);
        float p1 = __expf(s[kt][g * 4 + 1] - mrow);
        float p2 = __expf(s[kt][g * 4 + 2] - mrow);
        float p3 = __expf(s[kt][g * 4 + 3] - mrow);
        sum += (p0 + p1) + (p2 + p3);
        c[kt][2 * g]     = cvt_pk_bf16(p0, p1);
        c[kt][2 * g + 1] = cvt_pk_bf16(p2, p3);
      }
    sum += __shfl_xor(sum, 32);
    lrow += sum;

    u32 dx[2][8];
#pragma unroll
    for (int kt = 0; kt < 2; kt++)
#pragma unroll
      for (int j = 0; j < 8; j++)
        dx[kt][j] = (u32)__shfl_xor((int)c[kt][j], 32);

    if (pf) {
#pragma unroll
      for (int kt = 0; kt < 2; kt++)
#pragma unroll
        for (int g = 0; g < 4; g++)
          bb[kt * 4 + g] = *(const float4*)&biasq[(t + 1) * 64 + kt * 32 + 8 * g + 4 * hi];
    }

    __builtin_amdgcn_s_setprio(1);
#pragma unroll
    for (int kk = 0; kk < 4; kk++) {
      const int kt = kk >> 1, jA = 4 * (kk & 1);
      union { u32 u[4]; bf16x8 v; } pfg;
      pfg.u[0] = hi ? dx[kt][jA + 2] : c[kt][jA];
      pfg.u[1] = hi ? dx[kt][jA + 3] : c[kt][jA + 1];
      pfg.u[2] = hi ? c[kt][jA + 2]  : dx[kt][jA];
      pfg.u[3] = hi ? c[kt][jA + 3]  : dx[kt][jA + 1];
#pragma unroll
      for (int dt = 0; dt < 2; dt++) {
        bf16x8 va = *(const bf16x8*)&Vtlds[(dt * 32 + l31) * LDSS + kk * 16 + hi * 8];
        o[dt] = __builtin_amdgcn_mfma_f32_32x32x16_bf16(va, pfg.v, o[dt], 0, 0, 0);
      }
    }
    __builtin_amdgcn_s_setprio(0);
  }

  float inv = 1.0f / lrow;
  size_t obase = (size_t)(b * 2048 + qrow) * 512 + h * 64;
#pragma unroll
  for (int dt = 0; dt < 2; dt++)
#pragma unroll
    for (int g = 0; g < 4; g++) {
      uint2 pr;
      pr.x = cvt_pk_bf16(o[dt][4 * g + 0] * inv, o[dt][4 * g + 1] * inv);
      pr.y = cvt_pk_bf16(o[dt][4 * g + 2] * inv, o[dt][4 * g + 3] * inv);
      *(uint2*)&O[obase + dt * 32 + 8 * g + 4 * hi] = pr;
    }
}

// ---------------- output projection: 64x64 tile, reg-prefetch ----------------
__global__ __launch_bounds__(256) void outproj_kernel(
    const u16* __restrict__ Ob, const u16* __restrict__ woT,
    const float* __restrict__ bo, float* __restrict__ out) {
  __shared__ u16 Alds[64 * LDSS];
  __shared__ u16 Blds[64 * LDSS];
  int m0 = blockIdx.y * 64;
  int n0 = blockIdx.x * 64;
  int tid = threadIdx.x;
  int lane = tid & 63, w = tid >> 6;
  int wm = w >> 1, wn = w & 1;
  int l15 = lane & 15, l4 = lane >> 4;

  int r0 = tid >> 3, c8 = (tid & 7) * 8;
  uint4 ar0 = *(const uint4*)&Ob[(m0 + r0) * 512 + c8];
  uint4 ar1 = *(const uint4*)&Ob[(m0 + r0 + 32) * 512 + c8];
  uint4 br0 = *(const uint4*)&woT[(n0 + r0) * 512 + c8];
  uint4 br1 = *(const uint4*)&woT[(n0 + r0 + 32) * 512 + c8];

  f32x4 acc[2][2] = {};
  for (int ks = 0; ks < 8; ks++) {
    __syncthreads();
    *(uint4*)&Alds[r0 * LDSS + c8]        = ar0;
    *(uint4*)&Alds[(r0 + 32) * LDSS + c8] = ar1;
    *(uint4*)&Blds[r0 * LDSS + c8]        = br0;
    *(uint4*)&Blds[(r0 + 32) * LDSS + c8] = br1;
    __syncthreads();
    if (ks < 7) {
      int k0 = (ks + 1) * 64;
      ar0 = *(const uint4*)&Ob[(m0 + r0) * 512 + k0 + c8];
      ar1 = *(const uint4*)&Ob[(m0 + r0 + 32) * 512 + k0 + c8];
      br0 = *(const uint4*)&woT[(n0 + r0) * 512 + k0 + c8];
      br1 = *(const uint4*)&woT[(n0 + r0 + 32) * 512 + k0 + c8];
    }
#pragma unroll
    for (int kk = 0; kk < 2; kk++) {
      bf16x8 a[2], bfr[2];
#pragma unroll
      for (int f = 0; f < 2; f++) {
        a[f] = *(const bf16x8*)&Alds[(wm * 32 + f * 16 + l15) * LDSS + kk * 32 + l4 * 8];
        bfr[f] = *(const bf16x8*)&Blds[(wn * 32 + f * 16 + l15) * LDSS + kk * 32 + l4 * 8];
      }
#pragma unroll
      for (int fm = 0; fm < 2; fm++)
#pragma unroll
        for (int fn = 0; fn < 2; fn++)
          acc[fm][fn] = __builtin_amdgcn_mfma_f32_16x16x32_bf16(a[fm], bfr[fn], acc[fm][fn], 0, 0, 0);
    }
  }
#pragma unroll
  for (int fm = 0; fm < 2; fm++)
#pragma unroll
    for (int fn = 0; fn < 2; fn++)
#pragma unroll
      for (int r = 0; r < 4; r++) {
        int row = wm * 32 + fm * 16 + l4 * 4 + r;
        int col = wn * 32 + fn * 16 + l15;
        out[(size_t)(m0 + row) * 512 + n0 + col] = acc[fm][fn][r] + bo[n0 + col];
      }
}

extern "C" void kernel_launch(void* const* d_in, const int* in_sizes, int n_in,
                              void* d_out, int out_size, void* d_ws, size_t ws_size,
                              hipStream_t stream) {
  const float* x    = (const float*)d_in[0];
  const float* bias = (const float*)d_in[1];
  const float* wq   = (const float*)d_in[2];
  const float* bq   = (const float*)d_in[3];
  const float* wk   = (const float*)d_in[4];
  const float* bk   = (const float*)d_in[5];
  const float* wv   = (const float*)d_in[6];
  const float* bv   = (const float*)d_in[7];
  const float* wo   = (const float*)d_in[8];
  const float* bo   = (const float*)d_in[9];
  float* out = (float*)d_out;

  char* ws = (char*)d_ws;
  u16* xb  = (u16*)(ws + 0);
  u16* wqT = (u16*)(ws + 8388608);
  u16* wkT = (u16*)(ws + 8912896);
  u16* wvT = (u16*)(ws + 9437184);
  u16* woT = (u16*)(ws + 9961472);
  u16* Qb  = (u16*)(ws + 10485760);
  u16* Kb  = (u16*)(ws + 18874368);
  u16* VtB = (u16*)(ws + 27262976);
  u16* Ob  = (u16*)(ws + 35651584);

  hipLaunchKernelGGL(cast_x_kernel, dim3(2048), dim3(256), 0, stream, x, xb);
  hipLaunchKernelGGL(cast_wT_kernel, dim3(8, 8, 4), dim3(256), 0, stream,
                     wq, wk, wv, wo, wqT, wkT, wvT, woT);
  hipLaunchKernelGGL(proj_kernel, dim3(8, 128, 3), dim3(256), 0, stream,
                     xb, wqT, wkT, wvT, bq, bk, bv, Qb, Kb, VtB);
  hipLaunchKernelGGL(attn_kernel, dim3(16, 8, 4), dim3(256), 0, stream,
                     Qb, Kb, VtB, bias, Ob);
  hipLaunchKernelGGL(outproj_kernel, dim3(8, 128), dim3(256), 0, stream,
                     Ob, woT, bo, out);
}